// Round 1
// baseline (11721.250 us; speedup 1.0000x reference)
//
#include <hip/hip_runtime.h>

#define NN 100000      // nodes
#define NE 1000000     // edges per relation
#define RR 4           // relations
#define GG 256         // graphs
#define DHID 128       // feature width (DIN == DH == 128)
#define NCLS 10        // classes

// ---------------------------------------------------------------- degrees ---
__global__ __launch_bounds__(256) void degree_count(const int* __restrict__ edges,
                                                    int* __restrict__ cnt_out,
                                                    int* __restrict__ cnt_in) {
    int t = blockIdx.x * 256 + threadIdx.x;
    if (t >= RR * NE) return;
    int r = t / NE;
    int e = t - r * NE;
    const int* base = edges + (size_t)r * 2 * NE;
    atomicAdd(&cnt_out[r * NN + base[e]], 1);
    atomicAdd(&cnt_in[r * NN + base[NE + e]], 1);
}

// in-place: int degree count -> float rsqrt(max(deg,1)), over 2*R*N entries
__global__ __launch_bounds__(256) void deg_to_scale(int* __restrict__ cnt) {
    int t = blockIdx.x * 256 + threadIdx.x;
    if (t >= 2 * RR * NN) return;
    int c = cnt[t];
    float f = (float)(c < 1 ? 1 : c);
    ((float*)cnt)[t] = rsqrtf(f);
}

// ------------------------------------------------------------- bias init ----
// h_out[n][j] = sum_r b[r][j]   (vectorized float4)
__global__ __launch_bounds__(256) void init_bias(float* __restrict__ h,
                                                 const float* __restrict__ b) {
    size_t i = ((size_t)blockIdx.x * 256 + threadIdx.x) * 4;
    if (i >= (size_t)NN * DHID) return;
    int j = (int)(i & (DHID - 1));
    float4 b0 = *(const float4*)&b[0 * DHID + j];
    float4 b1 = *(const float4*)&b[1 * DHID + j];
    float4 b2 = *(const float4*)&b[2 * DHID + j];
    float4 b3 = *(const float4*)&b[3 * DHID + j];
    float4 s;
    s.x = b0.x + b1.x + b2.x + b3.x;
    s.y = b0.y + b1.y + b2.y + b3.y;
    s.z = b0.z + b1.z + b2.z + b3.z;
    s.w = b0.w + b1.w + b2.w + b3.w;
    *(float4*)&h[i] = s;
}

// ---------------------------------------------------------------- GEMM ------
// z[n][:] = (h_in[n][:] * sc[n]) @ W   for 64 rows per block.
// A-tile staged (scaled) in LDS; W streamed from global (L1/L2-resident).
__global__ __launch_bounds__(256) void matmul_scaled(const float* __restrict__ hin,
                                                     const float* __restrict__ sc,
                                                     const float* __restrict__ W,
                                                     float* __restrict__ z,
                                                     int nrows) {
    __shared__ float As[64 * 132];   // 64 rows, stride 132 (pad vs bank conflicts)
    const int tid = threadIdx.x;
    const int rowbase = blockIdx.x * 64;

    // stage A (scaled by sc) : 64*128 floats = 2048 float4, 8 per thread
    #pragma unroll
    for (int i = 0; i < 8; ++i) {
        int fi = i * 256 + tid;          // float4 index
        int rr = fi >> 5;                // 32 float4 per row
        int kk = (fi & 31) * 4;
        int row = rowbase + rr;
        float4 a = make_float4(0.f, 0.f, 0.f, 0.f);
        float s = 0.f;
        if (row < nrows) {
            a = *(const float4*)&hin[(size_t)row * DHID + kk];
            s = sc[row];
        }
        float* dst = &As[rr * 132 + kk];
        dst[0] = a.x * s; dst[1] = a.y * s; dst[2] = a.z * s; dst[3] = a.w * s;
    }
    __syncthreads();

    const int rp = tid >> 3;          // 0..31 row-pair
    const int cb = tid & 7;           // 0..7 col base
    const int r0 = rp * 2, r1 = r0 + 1;
    const float4* Wv = (const float4*)W;

    float acc0[16], acc1[16];
    #pragma unroll
    for (int i = 0; i < 16; ++i) { acc0[i] = 0.f; acc1[i] = 0.f; }

    for (int k = 0; k < 128; k += 4) {
        float4 a0 = *(const float4*)&As[r0 * 132 + k];
        float4 a1 = *(const float4*)&As[r1 * 132 + k];
        float x0[4] = {a0.x, a0.y, a0.z, a0.w};
        float x1[4] = {a1.x, a1.y, a1.z, a1.w};
        #pragma unroll
        for (int kk = 0; kk < 4; ++kk) {
            #pragma unroll
            for (int g = 0; g < 4; ++g) {
                float4 w = Wv[(k + kk) * 32 + cb + 8 * g];
                acc0[4 * g + 0] = fmaf(x0[kk], w.x, acc0[4 * g + 0]);
                acc0[4 * g + 1] = fmaf(x0[kk], w.y, acc0[4 * g + 1]);
                acc0[4 * g + 2] = fmaf(x0[kk], w.z, acc0[4 * g + 2]);
                acc0[4 * g + 3] = fmaf(x0[kk], w.w, acc0[4 * g + 3]);
                acc1[4 * g + 0] = fmaf(x1[kk], w.x, acc1[4 * g + 0]);
                acc1[4 * g + 1] = fmaf(x1[kk], w.y, acc1[4 * g + 1]);
                acc1[4 * g + 2] = fmaf(x1[kk], w.z, acc1[4 * g + 2]);
                acc1[4 * g + 3] = fmaf(x1[kk], w.w, acc1[4 * g + 3]);
            }
        }
    }

    int row0 = rowbase + r0;
    int row1 = rowbase + r1;
    if (row0 < nrows) {
        #pragma unroll
        for (int g = 0; g < 4; ++g) {
            float4 o = make_float4(acc0[4 * g], acc0[4 * g + 1], acc0[4 * g + 2], acc0[4 * g + 3]);
            *(float4*)&z[(size_t)row0 * DHID + cb * 4 + 32 * g] = o;
        }
    }
    if (row1 < nrows) {
        #pragma unroll
        for (int g = 0; g < 4; ++g) {
            float4 o = make_float4(acc1[4 * g], acc1[4 * g + 1], acc1[4 * g + 2], acc1[4 * g + 3]);
            *(float4*)&z[(size_t)row1 * DHID + cb * 4 + 32 * g] = o;
        }
    }
}

// ---------------------------------------------------------------- scatter ---
// h_out[dst][:] += si[dst] * z[src][:]   (one wave per edge, float2 per lane)
__global__ __launch_bounds__(256) void scatter_si(const float* __restrict__ z,
                                                  const float* __restrict__ si,
                                                  const int* __restrict__ src,
                                                  const int* __restrict__ dst,
                                                  float* __restrict__ hout) {
    long long t = (long long)blockIdx.x * 256 + threadIdx.x;
    int e = (int)(t >> 6);
    if (e >= NE) return;
    int lane = (int)(t & 63);
    int s = src[e];
    int d = dst[e];
    float sc = si[d];
    float2 v = *(const float2*)&z[(size_t)s * DHID + lane * 2];
    atomicAdd(&hout[(size_t)d * DHID + lane * 2 + 0], v.x * sc);
    atomicAdd(&hout[(size_t)d * DHID + lane * 2 + 1], v.y * sc);
}

// ---------------------------------------------------------------- relu ------
__global__ __launch_bounds__(256) void relu_k(float* __restrict__ h) {
    size_t i = ((size_t)blockIdx.x * 256 + threadIdx.x) * 4;
    if (i >= (size_t)NN * DHID) return;
    float4 v = *(float4*)&h[i];
    v.x = fmaxf(v.x, 0.f); v.y = fmaxf(v.y, 0.f);
    v.z = fmaxf(v.z, 0.f); v.w = fmaxf(v.w, 0.f);
    *(float4*)&h[i] = v;
}

// ---------------------------------------------------------------- pooling ---
__global__ __launch_bounds__(256) void count_nodes(const int* __restrict__ gid,
                                                   float* __restrict__ cnt) {
    int t = blockIdx.x * 256 + threadIdx.x;
    if (t < NN) atomicAdd(&cnt[gid[t]], 1.0f);
}

// graph_ids sorted -> segmented accumulation, few atomics per block
__global__ __launch_bounds__(256) void pool_sum(const float* __restrict__ h,
                                                const int* __restrict__ gid,
                                                float* __restrict__ hg) {
    int tid = threadIdx.x;
    int c = tid & 127;
    int grp = tid >> 7;
    int n0 = blockIdx.x * 64 + grp * 32;
    float acc = 0.f;
    int gcur = -1;
    for (int i = 0; i < 32; ++i) {
        int n = n0 + i;
        if (n >= NN) break;
        int g = gid[n];
        if (g != gcur) {
            if (gcur >= 0) atomicAdd(&hg[gcur * DHID + c], acc);
            gcur = g;
            acc = 0.f;
        }
        acc += h[(size_t)n * DHID + c];
    }
    if (gcur >= 0) atomicAdd(&hg[gcur * DHID + c], acc);
}

// ------------------------------------------------------------- classifier ---
__global__ __launch_bounds__(256) void classifier_k(const float* __restrict__ hg,
                                                    const float* __restrict__ cnt,
                                                    const float* __restrict__ Wc,
                                                    const float* __restrict__ bc,
                                                    float* __restrict__ out) {
    int t = blockIdx.x * 256 + threadIdx.x;
    if (t >= GG * NCLS) return;
    int g = t / NCLS;
    int c = t - g * NCLS;
    float inv = 1.0f / fmaxf(cnt[g], 1.0f);
    float acc = 0.f;
    #pragma unroll 4
    for (int k = 0; k < DHID; ++k)
        acc = fmaf(hg[g * DHID + k], Wc[k * NCLS + c], acc);
    out[t] = acc * inv + bc[c];
}

// ---------------------------------------------------------------- launch ----
extern "C" void kernel_launch(void* const* d_in, const int* in_sizes, int n_in,
                              void* d_out, int out_size, void* d_ws, size_t ws_size,
                              hipStream_t stream) {
    const float* features = (const float*)d_in[0];
    const int*   edges    = (const int*)d_in[1];
    const int*   gid      = (const int*)d_in[2];
    const float* W0       = (const float*)d_in[3];
    const float* b0       = (const float*)d_in[4];
    const float* Wl       = (const float*)d_in[5];
    const float* bl       = (const float*)d_in[6];
    const float* Wc       = (const float*)d_in[7];
    const float* bc       = (const float*)d_in[8];
    float* out = (float*)d_out;

    float* ws = (float*)d_ws;
    size_t off = 0;
    float* so  = ws + off; off += (size_t)RR * NN;
    float* si  = ws + off; off += (size_t)RR * NN;
    float* hA  = ws + off; off += (size_t)NN * DHID;
    float* hB  = ws + off; off += (size_t)NN * DHID;
    float* z   = ws + off; off += (size_t)NN * DHID;
    float* hg  = ws + off; off += (size_t)GG * DHID;
    float* cnt = ws + off; off += GG;
    if (ws_size < off * sizeof(float)) return;  // workspace too small

    // degrees -> rsqrt scales (so, si contiguous: one memset + one transform)
    hipMemsetAsync(so, 0, (size_t)2 * RR * NN * sizeof(int), stream);
    degree_count<<<(RR * NE + 255) / 256, 256, 0, stream>>>(edges, (int*)so, (int*)si);
    deg_to_scale<<<(2 * RR * NN + 255) / 256, 256, 0, stream>>>((int*)so);

    for (int l = 0; l < 3; ++l) {
        const float* hin  = (l == 0) ? features : ((l == 1) ? hA : hB);
        float*       hout = (l == 0) ? hA : ((l == 1) ? hB : hA);
        const float* Wp   = (l == 0) ? W0 : Wl + (size_t)(l - 1) * RR * DHID * DHID;
        const float* bp   = (l == 0) ? b0 : bl + (size_t)(l - 1) * RR * DHID;

        init_bias<<<(NN * DHID / 4 + 255) / 256, 256, 0, stream>>>(hout, bp);
        for (int r = 0; r < RR; ++r) {
            matmul_scaled<<<(NN + 63) / 64, 256, 0, stream>>>(
                hin, so + (size_t)r * NN, Wp + (size_t)r * DHID * DHID, z, NN);
            scatter_si<<<(int)(((long long)NE * 64) / 256), 256, 0, stream>>>(
                z, si + (size_t)r * NN,
                edges + (size_t)r * 2 * NE, edges + (size_t)r * 2 * NE + NE, hout);
        }
        relu_k<<<(NN * DHID / 4 + 255) / 256, 256, 0, stream>>>(hout);
    }

    // pooling (hg and cnt contiguous -> one memset)
    hipMemsetAsync(hg, 0, ((size_t)GG * DHID + GG) * sizeof(float), stream);
    count_nodes<<<(NN + 255) / 256, 256, 0, stream>>>(gid, cnt);
    pool_sum<<<(NN + 63) / 64, 256, 0, stream>>>(hA, gid, hg);
    classifier_k<<<(GG * NCLS + 255) / 256, 256, 0, stream>>>(hg, cnt, Wc, bc, out);
}

// Round 2
// 3398.962 us; speedup vs baseline: 3.4485x; 3.4485x over previous
//
#include <hip/hip_runtime.h>

#define NN 100000      // nodes
#define NE 1000000     // edges per relation
#define RR 4           // relations
#define GG 256         // graphs
#define DHID 128       // feature width (DIN == DH == 128)
#define NCLS 10        // classes
#define RN (RR * NN)   // virtual segments (r, dst)
#define NBLK ((RN + 1023) / 1024)

// ---------------------------------------------------------------- degrees ---
__global__ __launch_bounds__(256) void degree_count(const int* __restrict__ edges,
                                                    int* __restrict__ cnt_out,
                                                    int* __restrict__ cnt_in) {
    int t = blockIdx.x * 256 + threadIdx.x;
    if (t >= RR * NE) return;
    int r = t / NE;
    int e = t - r * NE;
    const int* base = edges + (size_t)r * 2 * NE;
    atomicAdd(&cnt_out[r * NN + base[e]], 1);
    atomicAdd(&cnt_in[r * NN + base[NE + e]], 1);
}

__global__ __launch_bounds__(256) void deg_to_scale(const int* __restrict__ cnt_out,
                                                    const int* __restrict__ cnt_in,
                                                    float* __restrict__ so,
                                                    float* __restrict__ si) {
    int t = blockIdx.x * 256 + threadIdx.x;
    if (t >= RN) return;
    int co = cnt_out[t], ci = cnt_in[t];
    so[t] = rsqrtf((float)(co < 1 ? 1 : co));
    si[t] = rsqrtf((float)(ci < 1 ? 1 : ci));
}

// ------------------------------------------------------------- CSR build ----
// exclusive scan over cnt_in[RN] -> row_ptr (and cursor copy), 3 kernels
__global__ __launch_bounds__(256) void scan_partial(const int* __restrict__ cnt,
                                                    int* __restrict__ partial) {
    __shared__ int sdat[256];
    int t = threadIdx.x;
    int base = blockIdx.x * 1024 + t * 4;
    int s = 0;
    #pragma unroll
    for (int i = 0; i < 4; ++i)
        if (base + i < RN) s += cnt[base + i];
    sdat[t] = s;
    __syncthreads();
    for (int off = 128; off > 0; off >>= 1) {
        if (t < off) sdat[t] += sdat[t + off];
        __syncthreads();
    }
    if (t == 0) partial[blockIdx.x] = sdat[0];
}

__global__ __launch_bounds__(512) void scan_block(int* __restrict__ partial) {
    __shared__ int s[512];
    int t = threadIdx.x;
    s[t] = (t < NBLK) ? partial[t] : 0;
    __syncthreads();
    for (int off = 1; off < 512; off <<= 1) {
        int v = (t >= off) ? s[t - off] : 0;
        __syncthreads();
        s[t] += v;
        __syncthreads();
    }
    if (t < NBLK) partial[t] = (t == 0) ? 0 : s[t - 1];
}

__global__ __launch_bounds__(256) void scan_write(const int* __restrict__ cnt,
                                                  const int* __restrict__ partial,
                                                  int* __restrict__ row_ptr,
                                                  int* __restrict__ cursor) {
    __shared__ int ssum[256];
    int t = threadIdx.x;
    int base = blockIdx.x * 1024 + t * 4;
    int c[4];
    #pragma unroll
    for (int i = 0; i < 4; ++i)
        c[i] = (base + i < RN) ? cnt[base + i] : 0;
    ssum[t] = c[0] + c[1] + c[2] + c[3];
    __syncthreads();
    for (int off = 1; off < 256; off <<= 1) {
        int v = (t >= off) ? ssum[t - off] : 0;
        __syncthreads();
        ssum[t] += v;
        __syncthreads();
    }
    int e = partial[blockIdx.x] + (t == 0 ? 0 : ssum[t - 1]);
    #pragma unroll
    for (int i = 0; i < 4; ++i) {
        if (base + i < RN) { row_ptr[base + i] = e; cursor[base + i] = e; e += c[i]; }
    }
    if (blockIdx.x == 0 && t == 0) row_ptr[RN] = RR * NE;
}

__global__ __launch_bounds__(256) void fill_csr(const int* __restrict__ edges,
                                                int* __restrict__ cursor,
                                                int* __restrict__ eidx) {
    int t = blockIdx.x * 256 + threadIdx.x;
    if (t >= RR * NE) return;
    int r = t / NE;
    int e = t - r * NE;
    const int* eb = edges + (size_t)r * 2 * NE;
    int s = eb[e];
    int d = eb[NE + e];
    int pos = atomicAdd(&cursor[r * NN + d], 1);
    eidx[pos] = s;
}

// ------------------------------------------------------------- layer --------
// One kernel = one full HeteroGraphConv layer + bias + ReLU.
// Per 64-row block: for each relation r { gather CSR segment (scaled by so[src],
// si[dst]) into LDS; GEMM-accumulate acc += As @ W_r in registers }, then add
// sum_r b[r], ReLU, pure store (no atomics, each row owned by one block).
__global__ __launch_bounds__(256) void layer_kernel(
    const float* __restrict__ hin, const float* __restrict__ so,
    const float* __restrict__ si, const int* __restrict__ row_ptr,
    const int* __restrict__ eidx, const float* __restrict__ W,
    const float* __restrict__ b, float* __restrict__ hout) {
    __shared__ float As[64 * 132];   // 64 rows, stride 132 (pad vs bank conflicts)
    const int tid  = threadIdx.x;
    const int wave = tid >> 6;
    const int lane = tid & 63;
    const int rowbase = blockIdx.x * 64;

    const int rp = tid >> 3;          // 0..31 row-pair
    const int cb = tid & 7;           // 0..7 col base
    const int r0 = rp * 2, r1 = r0 + 1;

    float acc0[16], acc1[16];
    #pragma unroll
    for (int i = 0; i < 16; ++i) { acc0[i] = 0.f; acc1[i] = 0.f; }

    for (int r = 0; r < RR; ++r) {
        const int rbase = r * NN;
        if (r) __syncthreads();       // previous GEMM done reading As

        // ---- gather phase: wave w owns rows w*16 .. w*16+15 ----
        for (int rr = 0; rr < 16; ++rr) {
            int row = wave * 16 + rr;
            int d = rowbase + row;
            float ax = 0.f, ay = 0.f;
            float sid = 0.f;
            if (d < NN) {
                int beg = row_ptr[rbase + d];
                int end = row_ptr[rbase + d + 1];
                sid = si[rbase + d];
                int j = beg;
                for (; j + 1 < end; j += 2) {
                    int s0 = eidx[j], s1 = eidx[j + 1];
                    float w0 = so[rbase + s0], w1 = so[rbase + s1];
                    float2 v0 = *(const float2*)&hin[(size_t)s0 * DHID + lane * 2];
                    float2 v1 = *(const float2*)&hin[(size_t)s1 * DHID + lane * 2];
                    ax = fmaf(w0, v0.x, ax); ay = fmaf(w0, v0.y, ay);
                    ax = fmaf(w1, v1.x, ax); ay = fmaf(w1, v1.y, ay);
                }
                if (j < end) {
                    int s0 = eidx[j];
                    float w0 = so[rbase + s0];
                    float2 v0 = *(const float2*)&hin[(size_t)s0 * DHID + lane * 2];
                    ax = fmaf(w0, v0.x, ax); ay = fmaf(w0, v0.y, ay);
                }
            }
            As[row * 132 + lane * 2]     = ax * sid;
            As[row * 132 + lane * 2 + 1] = ay * sid;
        }
        __syncthreads();

        // ---- GEMM phase: acc += As @ W_r ----
        const float4* Wv = (const float4*)(W + (size_t)r * DHID * DHID);
        for (int k = 0; k < 128; k += 4) {
            float4 a0 = *(const float4*)&As[r0 * 132 + k];
            float4 a1 = *(const float4*)&As[r1 * 132 + k];
            float x0[4] = {a0.x, a0.y, a0.z, a0.w};
            float x1[4] = {a1.x, a1.y, a1.z, a1.w};
            #pragma unroll
            for (int kk = 0; kk < 4; ++kk) {
                #pragma unroll
                for (int g = 0; g < 4; ++g) {
                    float4 w = Wv[(k + kk) * 32 + cb + 8 * g];
                    acc0[4 * g + 0] = fmaf(x0[kk], w.x, acc0[4 * g + 0]);
                    acc0[4 * g + 1] = fmaf(x0[kk], w.y, acc0[4 * g + 1]);
                    acc0[4 * g + 2] = fmaf(x0[kk], w.z, acc0[4 * g + 2]);
                    acc0[4 * g + 3] = fmaf(x0[kk], w.w, acc0[4 * g + 3]);
                    acc1[4 * g + 0] = fmaf(x1[kk], w.x, acc1[4 * g + 0]);
                    acc1[4 * g + 1] = fmaf(x1[kk], w.y, acc1[4 * g + 1]);
                    acc1[4 * g + 2] = fmaf(x1[kk], w.z, acc1[4 * g + 2]);
                    acc1[4 * g + 3] = fmaf(x1[kk], w.w, acc1[4 * g + 3]);
                }
            }
        }
    }

    // ---- epilogue: + sum_r b[r], ReLU, store ----
    int row0g = rowbase + r0;
    int row1g = rowbase + r1;
    #pragma unroll
    for (int g = 0; g < 4; ++g) {
        int col = cb * 4 + 32 * g;
        float4 bs = *(const float4*)&b[0 * DHID + col];
        float4 bv1 = *(const float4*)&b[1 * DHID + col];
        float4 bv2 = *(const float4*)&b[2 * DHID + col];
        float4 bv3 = *(const float4*)&b[3 * DHID + col];
        bs.x += bv1.x + bv2.x + bv3.x;
        bs.y += bv1.y + bv2.y + bv3.y;
        bs.z += bv1.z + bv2.z + bv3.z;
        bs.w += bv1.w + bv2.w + bv3.w;
        if (row0g < NN) {
            float4 o;
            o.x = fmaxf(acc0[4 * g + 0] + bs.x, 0.f);
            o.y = fmaxf(acc0[4 * g + 1] + bs.y, 0.f);
            o.z = fmaxf(acc0[4 * g + 2] + bs.z, 0.f);
            o.w = fmaxf(acc0[4 * g + 3] + bs.w, 0.f);
            *(float4*)&hout[(size_t)row0g * DHID + col] = o;
        }
        if (row1g < NN) {
            float4 o;
            o.x = fmaxf(acc1[4 * g + 0] + bs.x, 0.f);
            o.y = fmaxf(acc1[4 * g + 1] + bs.y, 0.f);
            o.z = fmaxf(acc1[4 * g + 2] + bs.z, 0.f);
            o.w = fmaxf(acc1[4 * g + 3] + bs.w, 0.f);
            *(float4*)&hout[(size_t)row1g * DHID + col] = o;
        }
    }
}

// ---------------------------------------------------------------- pooling ---
__global__ __launch_bounds__(256) void count_nodes(const int* __restrict__ gid,
                                                   float* __restrict__ cnt) {
    int t = blockIdx.x * 256 + threadIdx.x;
    if (t < NN) atomicAdd(&cnt[gid[t]], 1.0f);
}

__global__ __launch_bounds__(256) void pool_sum(const float* __restrict__ h,
                                                const int* __restrict__ gid,
                                                float* __restrict__ hg) {
    int tid = threadIdx.x;
    int c = tid & 127;
    int grp = tid >> 7;
    int n0 = blockIdx.x * 64 + grp * 32;
    float acc = 0.f;
    int gcur = -1;
    for (int i = 0; i < 32; ++i) {
        int n = n0 + i;
        if (n >= NN) break;
        int g = gid[n];
        if (g != gcur) {
            if (gcur >= 0) atomicAdd(&hg[gcur * DHID + c], acc);
            gcur = g;
            acc = 0.f;
        }
        acc += h[(size_t)n * DHID + c];
    }
    if (gcur >= 0) atomicAdd(&hg[gcur * DHID + c], acc);
}

// ------------------------------------------------------------- classifier ---
__global__ __launch_bounds__(256) void classifier_k(const float* __restrict__ hg,
                                                    const float* __restrict__ cnt,
                                                    const float* __restrict__ Wc,
                                                    const float* __restrict__ bc,
                                                    float* __restrict__ out) {
    int t = blockIdx.x * 256 + threadIdx.x;
    if (t >= GG * NCLS) return;
    int g = t / NCLS;
    int c = t - g * NCLS;
    float inv = 1.0f / fmaxf(cnt[g], 1.0f);
    float acc = 0.f;
    #pragma unroll 4
    for (int k = 0; k < DHID; ++k)
        acc = fmaf(hg[g * DHID + k], Wc[k * NCLS + c], acc);
    out[t] = acc * inv + bc[c];
}

// ---------------------------------------------------------------- launch ----
extern "C" void kernel_launch(void* const* d_in, const int* in_sizes, int n_in,
                              void* d_out, int out_size, void* d_ws, size_t ws_size,
                              hipStream_t stream) {
    const float* features = (const float*)d_in[0];
    const int*   edges    = (const int*)d_in[1];
    const int*   gid      = (const int*)d_in[2];
    const float* W0       = (const float*)d_in[3];
    const float* b0       = (const float*)d_in[4];
    const float* Wl       = (const float*)d_in[5];
    const float* bl       = (const float*)d_in[6];
    const float* Wc       = (const float*)d_in[7];
    const float* bc       = (const float*)d_in[8];
    float* out = (float*)d_out;

    // ---- workspace carve-up (ints first, then floats) ----
    int* iw = (int*)d_ws;
    size_t off = 0;
    int* cnt_out = iw + off; off += RN;
    int* cnt_in  = iw + off; off += RN;
    int* row_ptr = iw + off; off += RN + 1;
    int* cursor  = iw + off; off += RN;
    int* partial = iw + off; off += 512;
    int* eidx    = iw + off; off += (size_t)RR * NE;
    float* fw = (float*)(iw + off);
    size_t foff = 0;
    float* so   = fw + foff; foff += RN;
    float* si   = fw + foff; foff += RN;
    float* hA   = fw + foff; foff += (size_t)NN * DHID;
    float* hB   = fw + foff; foff += (size_t)NN * DHID;
    float* hg   = fw + foff; foff += (size_t)GG * DHID;
    float* cntg = fw + foff; foff += GG;
    if (ws_size < (off + foff) * sizeof(int)) return;

    // ---- degrees, scales, CSR (edges constant -> build once per call) ----
    hipMemsetAsync(cnt_out, 0, (size_t)2 * RN * sizeof(int), stream);
    degree_count<<<(RR * NE + 255) / 256, 256, 0, stream>>>(edges, cnt_out, cnt_in);
    deg_to_scale<<<(RN + 255) / 256, 256, 0, stream>>>(cnt_out, cnt_in, so, si);
    scan_partial<<<NBLK, 256, 0, stream>>>(cnt_in, partial);
    scan_block<<<1, 512, 0, stream>>>(partial);
    scan_write<<<NBLK, 256, 0, stream>>>(cnt_in, partial, row_ptr, cursor);
    fill_csr<<<(RR * NE + 255) / 256, 256, 0, stream>>>(edges, cursor, eidx);

    // ---- 3 fused layers ----
    for (int l = 0; l < 3; ++l) {
        const float* hin  = (l == 0) ? features : ((l == 1) ? hA : hB);
        float*       hout = (l == 0) ? hA : ((l == 1) ? hB : hA);
        const float* Wp   = (l == 0) ? W0 : Wl + (size_t)(l - 1) * RR * DHID * DHID;
        const float* bp   = (l == 0) ? b0 : bl + (size_t)(l - 1) * RR * DHID;
        layer_kernel<<<(NN + 63) / 64, 256, 0, stream>>>(
            hin, so, si, row_ptr, eidx, Wp, bp, hout);
    }

    // ---- pooling + classifier ----
    hipMemsetAsync(hg, 0, ((size_t)GG * DHID + GG) * sizeof(float), stream);
    count_nodes<<<(NN + 255) / 256, 256, 0, stream>>>(gid, cntg);
    pool_sum<<<(NN + 63) / 64, 256, 0, stream>>>(hA, gid, hg);
    classifier_k<<<(GG * NCLS + 255) / 256, 256, 0, stream>>>(hg, cntg, Wc, bc, out);
}